// Round 12
// baseline (101.933 us; speedup 1.0000x reference)
//
#include <hip/hip_runtime.h>

#define KDIM   128
#define NELEM  8388608

typedef __attribute__((ext_vector_type(4))) float f32x4;
typedef __attribute__((ext_vector_type(2))) int   int2v;

__device__ inline f32x4 mfma8(long long a, long long b, f32x4 c) {
  return __builtin_amdgcn_mfma_f32_16x16x32_fp8_fp8(a, b, c, 0, 0, 0);
}
__device__ inline void gload16(const void* g, void* l) {
  __builtin_amdgcn_global_load_lds(
      (const __attribute__((address_space(1))) unsigned*)g,
      (__attribute__((address_space(3))) unsigned*)l, 16, 0, 0);
}
__device__ inline long long pk8(float4 v0, float4 v1) {   // 8 fp32 -> 8 fp8 e4m3 (RNE)
  int lo = __builtin_amdgcn_cvt_pk_fp8_f32(v0.x, v0.y, 0, false);
  lo     = __builtin_amdgcn_cvt_pk_fp8_f32(v0.z, v0.w, lo, true);
  int hi = __builtin_amdgcn_cvt_pk_fp8_f32(v1.x, v1.y, 0, false);
  hi     = __builtin_amdgcn_cvt_pk_fp8_f32(v1.z, v1.w, hi, true);
  int2v t; t.x = lo; t.y = hi;
  return __builtin_bit_cast(long long, t);
}
__device__ inline float packk(float s, int c) {
  return __builtin_bit_cast(float,
      (__builtin_bit_cast(unsigned, s) & 0xFFFFFC00u) | (unsigned)c);
}
__device__ inline float sumsq(float4 a, float4 b) {
  return a.x*a.x + a.y*a.y + a.z*a.z + a.w*a.w + b.x*b.x + b.y*b.y + b.z*b.z + b.w*b.w;
}
__device__ inline void merge8(float (&t)[8], int msk) {
  float o[8];
#pragma unroll
  for (int p = 0; p < 8; ++p) o[p] = __shfl_xor(t[p], msk);
  float m[8];
#pragma unroll
  for (int p = 0; p < 8; ++p) m[p] = fmaxf(t[p], o[7 - p]);
#pragma unroll
  for (int s = 4; s; s >>= 1)
#pragma unroll
    for (int i = 0; i < 8; ++i)
      if (!(i & s)) {
        float x = fmaxf(m[i], m[i | s]);
        m[i | s] = fminf(m[i], m[i | s]);
        m[i] = x;
      }
#pragma unroll
  for (int p = 0; p < 8; ++p) t[p] = m[p];
}

__global__ void vq_prep(const float* __restrict__ emb, unsigned char* __restrict__ ebf8,
                        float* __restrict__ esqm, unsigned long long* __restrict__ lossAcc,
                        unsigned* __restrict__ cnt) {
  int j = blockIdx.x, d = threadIdx.x;
  float v = emb[j * KDIM + d];
  float vs = v * 1024.0f;
  int p = __builtin_amdgcn_cvt_pk_fp8_f32(vs, vs, 0, false);
  ebf8[j * KDIM + (d ^ ((j & 15) << 3))] = (unsigned char)(p & 0xFF);
  float s = v * v;
#pragma unroll
  for (int m = 1; m <= 32; m <<= 1) s += __shfl_xor(s, m);
  __shared__ float w[2];
  if ((d & 63) == 0) w[d >> 6] = s;
  __syncthreads();
  if (d == 0) esqm[j] = -512.0f * (w[0] + w[1]);
  if (j == 0 && d == 0) { lossAcc[0] = 0ULL; cnt[0] = 0u; }
}

__device__ inline void write_rows(const float* __restrict__ emb, float* __restrict__ outp,
                                  int grow0, int idx, int lane) {
#pragma unroll 4
  for (int r = 0; r < 16; ++r) {
    int s2 = __shfl(idx, r);
    float2 qv = *(const float2*)(emb + (size_t)s2 * KDIM + lane * 2);
    *(float2*)(outp + (size_t)(grow0 + r) * KDIM + lane * 2) = qv;
  }
}

// MODE: 0=stage-only 1=+ds_reads 2=+MFMA 3=+select 4=FULL(real output)
template <int MODE>
__global__ __launch_bounds__(1024, 4) void vq_main(
    const float* __restrict__ lat, const float* __restrict__ emb,
    const int* __restrict__ ksel, const unsigned char* __restrict__ ebf8,
    const float* __restrict__ esqm, float* __restrict__ out,
    unsigned long long* __restrict__ lossAcc, unsigned* __restrict__ cnt,
    float* __restrict__ loss) {
  __shared__ __align__(16) unsigned char smem[131072 + 4096 + 64];
  float* esqmLds = (float*)(smem + 131072);
  float* wLds    = (float*)(smem + 131072 + 4096);

  const int tid = threadIdx.x, lane = tid & 63, wid = tid >> 6;
  const int n = lane & 15, hi = lane >> 4;
  const int gR0 = blockIdx.x * 256;

  // --- identical prologue for all modes ---
  const float* rp0 = lat + (size_t)(gR0 + wid * 16 + n) * KDIM + hi * 8;
  float4 p0[4], p1[4];
#pragma unroll
  for (int ks = 0; ks < 4; ++ks) {
    p0[ks] = *(const float4*)(rp0 + ks * 32);
    p1[ks] = *(const float4*)(rp0 + ks * 32 + 4);
  }
  {
    const char* src = (const char*)ebf8 + tid * 16;
    char* dst = (char*)smem + tid * 16;
#pragma unroll
    for (int qq = 0; qq < 8; ++qq) gload16(src + qq * 16384, dst + qq * 16384);
    if (tid < 256) gload16((const char*)esqm + tid * 16, (char*)esqmLds + tid * 16);
  }
  float fsq0;
  long long b00, b01, b02, b03;
  {
    float s = 0.f;
#pragma unroll
    for (int ks = 0; ks < 4; ++ks) s += sumsq(p0[ks], p1[ks]);
    s += __shfl_xor(s, 16); s += __shfl_xor(s, 32);
    fsq0 = s;
    b00 = pk8(p0[0], p1[0]); b01 = pk8(p0[1], p1[1]);
    b02 = pk8(p0[2], p1[2]); b03 = pk8(p0[3], p1[3]);
  }
  asm volatile("s_waitcnt vmcnt(0)" ::: "memory");
  __builtin_amdgcn_s_barrier();

  const unsigned char* ab = smem + n * 128 + ((hi ^ (n & 3)) << 3);
  const int nh = n >> 2;
  const unsigned char* bk0 = ab + ((0 ^ nh) << 5);
  const unsigned char* bk1 = ab + ((1 ^ nh) << 5);
  const unsigned char* bk2 = ab + ((2 ^ nh) << 5);
  const unsigned char* bk3 = ab + ((3 ^ nh) << 5);

  if constexpr (MODE == 0) {   // stage-only floor
    long long v = *(const long long*)(bk0);
    asm volatile("" :: "v"(v), "v"(b00), "v"(b01), "v"(b02), "v"(b03), "v"(fsq0));
    return;
  }

  const float NINF = __builtin_bit_cast(float, 0xFF800000u);
  float top0[8];
#pragma unroll
  for (int p = 0; p < 8; ++p) top0[p] = NINF;

  int cid = hi * 4;
#pragma unroll 2
  for (int pp = 0; pp < 32; ++pp) {
    const int off = pp * 4096;
    const float* eb = esqmLds + pp * 32 + hi * 4;
    f32x4 e0 = *(const f32x4*)(eb);
    f32x4 e1 = *(const f32x4*)(eb + 16);
    long long t0 = *(const long long*)(bk0 + off);
    long long t1 = *(const long long*)(bk1 + off);
    long long t2 = *(const long long*)(bk2 + off);
    long long t3 = *(const long long*)(bk3 + off);
    long long u0 = *(const long long*)(bk0 + off + 2048);
    long long u1 = *(const long long*)(bk1 + off + 2048);
    long long u2 = *(const long long*)(bk2 + off + 2048);
    long long u3 = *(const long long*)(bk3 + off + 2048);
    if constexpr (MODE == 1) {   // LDS-pipe only
      asm volatile("" :: "v"(t0), "v"(t1), "v"(t2), "v"(t3),
                        "v"(u0), "v"(u1), "v"(u2), "v"(u3));
      asm volatile("" :: "v"(e0[0]), "v"(e1[0]));
      continue;
    }
    f32x4 a0 = e0, a1 = e1;
    f32x4 c0 = (f32x4){0.f, 0.f, 0.f, 0.f};
    f32x4 c1 = (f32x4){0.f, 0.f, 0.f, 0.f};
    a0 = mfma8(t0, b00, a0);
    a0 = mfma8(t1, b01, a0);
    c0 = mfma8(t2, b02, c0);
    c0 = mfma8(t3, b03, c0);
    a1 = mfma8(u0, b00, a1);
    a1 = mfma8(u1, b01, a1);
    c1 = mfma8(u2, b02, c1);
    c1 = mfma8(u3, b03, c1);
    a0 += c0;
    a1 += c1;
    if constexpr (MODE == 2) {   // +MFMA, no select
      asm volatile("" :: "v"(a0[0]), "v"(a0[1]), "v"(a0[2]), "v"(a0[3]),
                        "v"(a1[0]), "v"(a1[1]), "v"(a1[2]), "v"(a1[3]));
      continue;
    }
    float k0 = packk(a0[0], cid + 0),  k1 = packk(a0[1], cid + 1);
    float k2 = packk(a0[2], cid + 2),  k3 = packk(a0[3], cid + 3);
    float k4 = packk(a1[0], cid + 16), k5 = packk(a1[1], cid + 17);
    float k6 = packk(a1[2], cid + 18), k7 = packk(a1[3], cid + 19);
    float x = fmaxf(fmaxf(fmaxf(k0, k1), fmaxf(k2, k3)),
                    fmaxf(fmaxf(k4, k5), fmaxf(k6, k7)));
#pragma unroll
    for (int p = 0; p < 8; ++p) {
      float mx = fmaxf(top0[p], x);
      x = fminf(top0[p], x);
      top0[p] = mx;
    }
    cid += 32;
  }

  if constexpr (MODE == 1 || MODE == 2) return;

  int kk = ksel[lane & 7];
  kk = kk < 0 ? 0 : (kk > 7 ? 7 : kk);
  merge8(top0, 16); merge8(top0, 32);
  float sel0 = top0[0];
#pragma unroll
  for (int p = 1; p < 8; ++p) sel0 = (kk == p) ? top0[p] : sel0;
  unsigned sb0 = __builtin_bit_cast(unsigned, sel0);
  int idx0 = (int)(sb0 & 1023u);
  float rl0 = fsq0 - __builtin_bit_cast(float, sb0 & 0xFFFFFC00u) * (1.0f / 512.0f);

  if constexpr (MODE == 3) {   // +select, no write/loss
    asm volatile("" :: "v"(idx0), "v"(rl0));
    return;
  }

  // ---- MODE 4: FULL ----
  write_rows(emb, out, gR0 + wid * 16, idx0, lane);

  float c = (lane < 16) ? rl0 : 0.f;
#pragma unroll
  for (int m = 1; m <= 32; m <<= 1) c += __shfl_xor(c, m);
  if (lane == 0) wLds[wid] = c;
  __syncthreads();
  if (tid == 0) {
    double bs = 0.0;
#pragma unroll
    for (int w = 0; w < 16; ++w) bs += (double)wLds[w];
    long long iv = (long long)(bs * 1048576.0 + 0.5);
    atomicAdd(lossAcc, (unsigned long long)iv);
    __threadfence();
    unsigned done = atomicAdd(cnt, 1u);
    if (done == 255u) {
      unsigned long long tot = atomicAdd(lossAcc, 0ULL);
      loss[0] = (float)((double)(long long)tot * (1.25 / (1048576.0 * 8388608.0)));
    }
  }
}

extern "C" void kernel_launch(void* const* d_in, const int* in_sizes, int n_in,
                              void* d_out, int out_size, void* d_ws, size_t ws_size,
                              hipStream_t stream) {
  const float* lat = (const float*)d_in[0];
  const float* emb = (const float*)d_in[1];
  const int* ksel = (const int*)d_in[2];
  float* out = (float*)d_out;

  unsigned char* ebf8 = (unsigned char*)d_ws;
  float* esqm = (float*)((char*)d_ws + 131072);
  unsigned long long* lossAcc = (unsigned long long*)((char*)d_ws + 135168);
  unsigned* cnt = (unsigned*)((char*)d_ws + 135176);

  vq_prep<<<1024, 128, 0, stream>>>(emb, ebf8, esqm, lossAcc, cnt);
  // ablation ladder (diagnostic; FULL last produces the real output)
  vq_main<0><<<256, 1024, 0, stream>>>(lat, emb, ksel, ebf8, esqm, out, lossAcc, cnt, out + NELEM);
  vq_main<1><<<256, 1024, 0, stream>>>(lat, emb, ksel, ebf8, esqm, out, lossAcc, cnt, out + NELEM);
  vq_main<2><<<256, 1024, 0, stream>>>(lat, emb, ksel, ebf8, esqm, out, lossAcc, cnt, out + NELEM);
  vq_main<3><<<256, 1024, 0, stream>>>(lat, emb, ksel, ebf8, esqm, out, lossAcc, cnt, out + NELEM);
  vq_main<4><<<256, 1024, 0, stream>>>(lat, emb, ksel, ebf8, esqm, out, lossAcc, cnt, out + NELEM);
}

// Round 13
// 61.652 us; speedup vs baseline: 1.6534x; 1.6534x over previous
//
#include <hip/hip_runtime.h>

#define KDIM   128
#define NELEM  8388608

typedef __attribute__((ext_vector_type(4))) float f32x4;
typedef __attribute__((ext_vector_type(2))) int   int2v;

__device__ inline f32x4 mfma8(long long a, long long b, f32x4 c) {
  return __builtin_amdgcn_mfma_f32_16x16x32_fp8_fp8(a, b, c, 0, 0, 0);
}
__device__ inline void gload16(const void* g, void* l) {
  __builtin_amdgcn_global_load_lds(
      (const __attribute__((address_space(1))) unsigned*)g,
      (__attribute__((address_space(3))) unsigned*)l, 16, 0, 0);
}
__device__ inline long long pk8(float4 v0, float4 v1) {   // 8 fp32 -> 8 fp8 e4m3 (RNE)
  int lo = __builtin_amdgcn_cvt_pk_fp8_f32(v0.x, v0.y, 0, false);
  lo     = __builtin_amdgcn_cvt_pk_fp8_f32(v0.z, v0.w, lo, true);
  int hi = __builtin_amdgcn_cvt_pk_fp8_f32(v1.x, v1.y, 0, false);
  hi     = __builtin_amdgcn_cvt_pk_fp8_f32(v1.z, v1.w, hi, true);
  int2v t; t.x = lo; t.y = hi;
  return __builtin_bit_cast(long long, t);
}
__device__ inline float packk(float s, int c) {           // code id -> low-10 mantissa bits
  return __builtin_bit_cast(float,
      (__builtin_bit_cast(unsigned, s) & 0xFFFFFC00u) | (unsigned)c);
}
__device__ inline float sumsq(float4 a, float4 b) {
  return a.x*a.x + a.y*a.y + a.z*a.z + a.w*a.w + b.x*b.x + b.y*b.y + b.z*b.z + b.w*b.w;
}
// merge this lane's sorted-desc top8 with lane^msk's (bitonic top-8 of 16)
__device__ inline void merge8(float (&t)[8], int msk) {
  float o[8];
#pragma unroll
  for (int p = 0; p < 8; ++p) o[p] = __shfl_xor(t[p], msk);
  float m[8];
#pragma unroll
  for (int p = 0; p < 8; ++p) m[p] = fmaxf(t[p], o[7 - p]);
#pragma unroll
  for (int s = 4; s; s >>= 1)
#pragma unroll
    for (int i = 0; i < 8; ++i)
      if (!(i & s)) {
        float x = fmaxf(m[i], m[i | s]);
        m[i | s] = fminf(m[i], m[i | s]);
        m[i] = x;
      }
#pragma unroll
  for (int p = 0; p < 8; ++p) t[p] = m[p];
}

// ---- prep: emb -> fp8 (x1024, K-XOR-swizzled) + -512*||e||^2 + zero accumulators ----
__global__ void vq_prep(const float* __restrict__ emb, unsigned char* __restrict__ ebf8,
                        float* __restrict__ esqm, unsigned long long* __restrict__ lossAcc,
                        unsigned* __restrict__ cnt) {
  int j = blockIdx.x, d = threadIdx.x;
  float v = emb[j * KDIM + d];
  float vs = v * 1024.0f;
  int p = __builtin_amdgcn_cvt_pk_fp8_f32(vs, vs, 0, false);
  ebf8[j * KDIM + (d ^ ((j & 15) << 3))] = (unsigned char)(p & 0xFF);
  float s = v * v;
#pragma unroll
  for (int m = 1; m <= 32; m <<= 1) s += __shfl_xor(s, m);
  __shared__ float w[2];
  if ((d & 63) == 0) w[d >> 6] = s;
  __syncthreads();
  if (d == 0) esqm[j] = -512.0f * (w[0] + w[1]);
  if (j == 0 && d == 0) { lossAcc[0] = 0ULL; cnt[0] = 0u; }
}

// ---- A: block = (128 rows, codebook half); 2 resident/CU -> phases overlap ----
__global__ __launch_bounds__(512, 2) void vq_scan(
    const float* __restrict__ lat, const unsigned char* __restrict__ ebf8,
    const float* __restrict__ esqm, float* __restrict__ fsq_g,
    float* __restrict__ lists_g) {
  __shared__ __align__(16) unsigned char smem[65536 + 2048];
  float* esqmLds = (float*)(smem + 65536);

  const int tid = threadIdx.x, lane = tid & 63, wid = tid >> 6;   // wid 0..7
  const int n = lane & 15, hi = lane >> 4;
  const int h = blockIdx.x & 1, rb = blockIdx.x >> 1;
  const int gR0 = rb * 128;

  // (a) this wave's 16 latent rows -> issue loads
  const float* rp0 = lat + (size_t)(gR0 + wid * 16 + n) * KDIM + hi * 8;
  float4 p0[4], p1[4];
#pragma unroll
  for (int ks = 0; ks < 4; ++ks) {
    p0[ks] = *(const float4*)(rp0 + ks * 32);
    p1[ks] = *(const float4*)(rp0 + ks * 32 + 4);
  }
  // (b) half-codebook (64 KB) + half-norms (2 KB) DMA -> LDS
  {
    const char* src = (const char*)ebf8 + h * 65536 + tid * 16;
    char* dst = (char*)smem + tid * 16;
#pragma unroll
    for (int qq = 0; qq < 8; ++qq) gload16(src + qq * 8192, dst + qq * 8192);
    if (tid < 128)
      gload16((const char*)(esqm + h * 512) + tid * 16, (char*)esqmLds + tid * 16);
  }
  // (c) frags (fp8) + exact ||f||^2 (written once, by half-0 blocks)
  float fsq0;
  long long b00, b01, b02, b03;
  {
    float s = 0.f;
#pragma unroll
    for (int ks = 0; ks < 4; ++ks) s += sumsq(p0[ks], p1[ks]);
    s += __shfl_xor(s, 16); s += __shfl_xor(s, 32);
    fsq0 = s;
    b00 = pk8(p0[0], p1[0]); b01 = pk8(p0[1], p1[1]);
    b02 = pk8(p0[2], p1[2]); b03 = pk8(p0[3], p1[3]);
  }
  if (h == 0 && hi == 0) fsq_g[gR0 + wid * 16 + n] = fsq0;
  asm volatile("s_waitcnt vmcnt(0)" ::: "memory");
  __builtin_amdgcn_s_barrier();

  // A-read addressing: byte = row*128 + ((ks*32+hi*8) ^ ((row&15)<<3))
  const unsigned char* ab = smem + n * 128 + ((hi ^ (n & 3)) << 3);
  const int nh = n >> 2;
  const unsigned char* bk0 = ab + ((0 ^ nh) << 5);
  const unsigned char* bk1 = ab + ((1 ^ nh) << 5);
  const unsigned char* bk2 = ab + ((2 ^ nh) << 5);
  const unsigned char* bk3 = ab + ((3 ^ nh) << 5);

  const float NINF = __builtin_bit_cast(float, 0xFF800000u);
  float top0[8];
#pragma unroll
  for (int p = 0; p < 8; ++p) top0[p] = NINF;

  int cid = h * 512 + hi * 4;
#pragma unroll 2
  for (int pp = 0; pp < 16; ++pp) {
    const int off = pp * 4096;
    const float* eb = esqmLds + pp * 32 + hi * 4;
    f32x4 a0 = *(const f32x4*)(eb);
    f32x4 a1 = *(const f32x4*)(eb + 16);
    f32x4 c0 = (f32x4){0.f, 0.f, 0.f, 0.f};
    f32x4 c1 = (f32x4){0.f, 0.f, 0.f, 0.f};
    a0 = mfma8(*(const long long*)(bk0 + off), b00, a0);
    a0 = mfma8(*(const long long*)(bk1 + off), b01, a0);
    c0 = mfma8(*(const long long*)(bk2 + off), b02, c0);
    c0 = mfma8(*(const long long*)(bk3 + off), b03, c0);
    a1 = mfma8(*(const long long*)(bk0 + off + 2048), b00, a1);
    a1 = mfma8(*(const long long*)(bk1 + off + 2048), b01, a1);
    c1 = mfma8(*(const long long*)(bk2 + off + 2048), b02, c1);
    c1 = mfma8(*(const long long*)(bk3 + off + 2048), b03, c1);
    a0 += c0;
    a1 += c1;
    float k0 = packk(a0[0], cid + 0),  k1 = packk(a0[1], cid + 1);
    float k2 = packk(a0[2], cid + 2),  k3 = packk(a0[3], cid + 3);
    float k4 = packk(a1[0], cid + 16), k5 = packk(a1[1], cid + 17);
    float k6 = packk(a1[2], cid + 18), k7 = packk(a1[3], cid + 19);
    float x = fmaxf(fmaxf(fmaxf(k0, k1), fmaxf(k2, k3)),
                    fmaxf(fmaxf(k4, k5), fmaxf(k6, k7)));
#pragma unroll
    for (int p = 0; p < 8; ++p) {            // descending top-8, branchless
      float mx = fmaxf(top0[p], x);
      x = fminf(top0[p], x);
      top0[p] = mx;
    }
    cid += 32;
  }

  // combine across hi-lanes -> per-row sorted top-8 of this half; write 32 B/row
  merge8(top0, 16); merge8(top0, 32);
  if (hi == 0) {
    float* dst = lists_g + ((size_t)(gR0 + wid * 16 + n) * 2 + h) * 8;
    *(float4*)(dst + 0) = make_float4(top0[0], top0[1], top0[2], top0[3]);
    *(float4*)(dst + 4) = make_float4(top0[4], top0[5], top0[6], top0[7]);
  }
}

// ---- B: merge 2 half-lists/row, pick k-th, gather + write + deterministic loss ----
__global__ __launch_bounds__(256) void vq_out(
    const float* __restrict__ emb, const int* __restrict__ ksel,
    const float* __restrict__ lists_g, const float* __restrict__ fsq_g,
    float* __restrict__ out, unsigned long long* __restrict__ lossAcc,
    unsigned* __restrict__ cnt, float* __restrict__ loss) {
  __shared__ __align__(16) float lbuf[128 * 20];   // 16 floats/row, stride 20 (16B-aligned)
  __shared__ int selLds[128];
  __shared__ float wLds[2];

  const int tid = threadIdx.x;
  const int lane = tid & 63, wid = tid >> 6;
  const int rB0 = blockIdx.x * 128;
  const float NINF = __builtin_bit_cast(float, 0xFF800000u);

  // stage 128 rows x 16 floats of lists into padded LDS
#pragma unroll
  for (int it = 0; it < 2; ++it) {
    int f4 = tid + it * 256;                 // float4 index; flat float f = 4*f4
    int f = f4 * 4;
    int row = f >> 4, col = f & 15;
    float4 v = *(const float4*)(lists_g + (size_t)rB0 * 16 + f);
    *(float4*)(&lbuf[row * 20 + col]) = v;
  }
  __syncthreads();

  float rl = 0.f;
  if (tid < 128) {
    const int row = rB0 + tid;
    int kk = ksel[row & 7]; kk = kk < 0 ? 0 : (kk > 7 ? 7 : kk);
    const float* base = lbuf + tid * 20;
    float ha = base[0], hb = base[8];
    int ia = 1, ib = 1;
    float sel;
    for (int s = 0;; ++s) {
      sel = fmaxf(ha, hb);
      if (s == kk) break;
      if (sel == ha) { ha = (ia < 8) ? base[ia] : NINF; ++ia; }
      else           { hb = (ib < 8) ? base[8 + ib] : NINF; ++ib; }
    }
    unsigned sb = __builtin_bit_cast(unsigned, sel);
    selLds[tid] = (int)(sb & 1023u);
    // row loss = ||f||^2 - 2*(f.e - ||e||^2/2) ; scores carry x1024 scale
    float val = __builtin_bit_cast(float, sb & 0xFFFFFC00u);
    rl = fsq_g[row] - val * (1.0f / 512.0f);
  }
#pragma unroll
  for (int m = 1; m <= 32; m <<= 1) rl += __shfl_xor(rl, m);
  if (lane == 0 && wid < 2) wLds[wid] = rl;
  __syncthreads();

  if (tid == 0) {
    double bs = (double)wLds[0] + (double)wLds[1];
    long long iv = (long long)(bs * 1048576.0 + 0.5);
    atomicAdd(lossAcc, (unsigned long long)iv);
    __threadfence();
    unsigned done = atomicAdd(cnt, 1u);
    if (done == 511u) {
      unsigned long long tot = atomicAdd(lossAcc, 0ULL);
      loss[0] = (float)((double)(long long)tot * (1.25 / (1048576.0 * 8388608.0)));
    }
  }

  // epilogue: gather selected fp32 code rows -> out (coalesced; emb L2-hot)
#pragma unroll
  for (int it = 0; it < 16; ++it) {
    int i = tid + it * 256;
    int row = i >> 5, c4 = i & 31;
    int s2 = selLds[row];
    float4 v = *(const float4*)(emb + (size_t)s2 * KDIM + c4 * 4);
    *(float4*)(out + (size_t)(rB0 + row) * KDIM + c4 * 4) = v;
  }
}

extern "C" void kernel_launch(void* const* d_in, const int* in_sizes, int n_in,
                              void* d_out, int out_size, void* d_ws, size_t ws_size,
                              hipStream_t stream) {
  const float* lat = (const float*)d_in[0];   // [8192,1024] fp32
  const float* emb = (const float*)d_in[1];   // [1024,128]  fp32
  const int* ksel = (const int*)d_in[2];      // [8] int32
  float* out = (float*)d_out;                 // quantized[8388608] + loss[1]

  unsigned char* ebf8 = (unsigned char*)d_ws;                 // 131072 B swizzled fp8 codes
  float* esqm = (float*)((char*)d_ws + 131072);               // 4096 B (-512*||e||^2)
  float* fsq_g = (float*)((char*)d_ws + 135168);              // 262144 B per-row ||f||^2
  float* lists_g = (float*)((char*)d_ws + 397312);            // 4 MB per-row 2x8 lists
  unsigned long long* lossAcc =
      (unsigned long long*)((char*)d_ws + 4591616);           // 8 B fixed-point loss
  unsigned* cnt = (unsigned*)((char*)d_ws + 4591624);         // 4 B block counter

  vq_prep<<<1024, 128, 0, stream>>>(emb, ebf8, esqm, lossAcc, cnt);
  vq_scan<<<1024, 512, 0, stream>>>(lat, ebf8, esqm, fsq_g, lists_g);
  vq_out<<<512, 256, 0, stream>>>(emb, ksel, lists_g, fsq_g, out, lossAcc, cnt,
                                  out + NELEM);
}

// Round 14
// 44.849 us; speedup vs baseline: 2.2728x; 1.3747x over previous
//
#include <hip/hip_runtime.h>

#define KDIM   128
#define NELEM  8388608

typedef __attribute__((ext_vector_type(4))) float f32x4;
typedef __attribute__((ext_vector_type(2))) int   int2v;

__device__ inline f32x4 mfma8(long long a, long long b, f32x4 c) {
  return __builtin_amdgcn_mfma_f32_16x16x32_fp8_fp8(a, b, c, 0, 0, 0);
}
__device__ inline void gload16(const void* g, void* l) {
  __builtin_amdgcn_global_load_lds(
      (const __attribute__((address_space(1))) unsigned*)g,
      (__attribute__((address_space(3))) unsigned*)l, 16, 0, 0);
}
__device__ inline long long pk8(float4 v0, float4 v1) {   // 8 fp32 -> 8 fp8 e4m3 (RNE)
  int lo = __builtin_amdgcn_cvt_pk_fp8_f32(v0.x, v0.y, 0, false);
  lo     = __builtin_amdgcn_cvt_pk_fp8_f32(v0.z, v0.w, lo, true);
  int hi = __builtin_amdgcn_cvt_pk_fp8_f32(v1.x, v1.y, 0, false);
  hi     = __builtin_amdgcn_cvt_pk_fp8_f32(v1.z, v1.w, hi, true);
  int2v t; t.x = lo; t.y = hi;
  return __builtin_bit_cast(long long, t);
}
__device__ inline float packk(float s, int c) {           // code id -> low-10 mantissa bits
  return __builtin_bit_cast(float,
      (__builtin_bit_cast(unsigned, s) & 0xFFFFFC00u) | (unsigned)c);
}
__device__ inline float sumsq(float4 a, float4 b) {
  return a.x*a.x + a.y*a.y + a.z*a.z + a.w*a.w + b.x*b.x + b.y*b.y + b.z*b.z + b.w*b.w;
}
// merge this lane's sorted-desc top8 with lane^msk's (bitonic top-8 of 16)
__device__ inline void merge8(float (&t)[8], int msk) {
  float o[8];
#pragma unroll
  for (int p = 0; p < 8; ++p) o[p] = __shfl_xor(t[p], msk);
  float m[8];
#pragma unroll
  for (int p = 0; p < 8; ++p) m[p] = fmaxf(t[p], o[7 - p]);
#pragma unroll
  for (int s = 4; s; s >>= 1)
#pragma unroll
    for (int i = 0; i < 8; ++i)
      if (!(i & s)) {
        float x = fmaxf(m[i], m[i | s]);
        m[i | s] = fminf(m[i], m[i | s]);
        m[i] = x;
      }
#pragma unroll
  for (int p = 0; p < 8; ++p) t[p] = m[p];
}
// branchless descending top-8 insert of one key
__device__ inline void ins8(float (&top)[8], float x) {
#pragma unroll
  for (int p = 0; p < 8; ++p) {
    float mx = fmaxf(top[p], x);
    x = fminf(top[p], x);
    top[p] = mx;
  }
}

// ---- prep: emb -> fp8 (x1024, K-XOR-swizzled) + -512*||e||^2 + zero accumulators ----
__global__ void vq_prep(const float* __restrict__ emb, unsigned char* __restrict__ ebf8,
                        float* __restrict__ esqm, unsigned long long* __restrict__ lossAcc,
                        unsigned* __restrict__ cnt) {
  int j = blockIdx.x, d = threadIdx.x;
  float v = emb[j * KDIM + d];
  float vs = v * 1024.0f;
  int p = __builtin_amdgcn_cvt_pk_fp8_f32(vs, vs, 0, false);
  ebf8[j * KDIM + (d ^ ((j & 15) << 3))] = (unsigned char)(p & 0xFF);
  float s = v * v;
#pragma unroll
  for (int m = 1; m <= 32; m <<= 1) s += __shfl_xor(s, m);
  __shared__ float w[2];
  if ((d & 63) == 0) w[d >> 6] = s;
  __syncthreads();
  if (d == 0) esqm[j] = -512.0f * (w[0] + w[1]);   // score = 1024*(f.e - ||e||^2/2)
  if (j == 0 && d == 0) { lossAcc[0] = 0ULL; cnt[0] = 0u; }
}

__device__ inline void write_rows(const float* __restrict__ emb, float* __restrict__ outp,
                                  int grow0, int idx, int lane) {
#pragma unroll 4
  for (int r = 0; r < 16; ++r) {
    int s2 = __shfl(idx, r);
    float2 qv = *(const float2*)(emb + (size_t)s2 * KDIM + lane * 2);
    *(float2*)(outp + (size_t)(grow0 + r) * KDIM + lane * 2) = qv;
  }
}

// ---- main: 1 block/CU (512 thr, 8 waves), 32 rows/wave, STAGGERED group order ----
__global__ __launch_bounds__(512, 1) void vq_main(
    const float* __restrict__ lat, const float* __restrict__ emb,
    const int* __restrict__ ksel, const unsigned char* __restrict__ ebf8,
    const float* __restrict__ esqm, float* __restrict__ out,
    unsigned long long* __restrict__ lossAcc, unsigned* __restrict__ cnt,
    float* __restrict__ loss) {
  __shared__ __align__(16) unsigned char smem[131072 + 4096 + 64];
  float* esqmLds = (float*)(smem + 131072);
  float* wLds    = (float*)(smem + 131072 + 4096);

  const int tid = threadIdx.x, lane = tid & 63, wid = tid >> 6;   // wid 0..7
  const int n = lane & 15, hi = lane >> 4;
  const int gR0 = blockIdx.x * 256;

  // (a) row-set 0 (wid*32 + 0..15) and row-set 1 (+16) -> issue loads
  const float* rp0 = lat + (size_t)(gR0 + wid * 32 + n) * KDIM + hi * 8;
  const float* rp1 = rp0 + 16 * KDIM;
  float4 p0[4], p1[4], q0[4], q1[4];
#pragma unroll
  for (int ks = 0; ks < 4; ++ks) {
    p0[ks] = *(const float4*)(rp0 + ks * 32);
    p1[ks] = *(const float4*)(rp0 + ks * 32 + 4);
    q0[ks] = *(const float4*)(rp1 + ks * 32);
    q1[ks] = *(const float4*)(rp1 + ks * 32 + 4);
  }
  // (b) codebook (128 KB) + norms (4 KB) DMA -> LDS (pre-swizzled; linear copy)
  {
    const char* src = (const char*)ebf8 + tid * 16;
    char* dst = (char*)smem + tid * 16;
#pragma unroll
    for (int qq = 0; qq < 16; ++qq) gload16(src + qq * 8192, dst + qq * 8192);
    if (tid < 256) gload16((const char*)esqm + tid * 16, (char*)esqmLds + tid * 16);
  }
  // (c) frags (fp8) + exact ||f||^2 per set
  float fsq0, fsq1;
  long long b00, b01, b02, b03, b10, b11, b12, b13;
  {
    float s0 = 0.f, s1 = 0.f;
#pragma unroll
    for (int ks = 0; ks < 4; ++ks) {
      s0 += sumsq(p0[ks], p1[ks]);
      s1 += sumsq(q0[ks], q1[ks]);
    }
    s0 += __shfl_xor(s0, 16); s0 += __shfl_xor(s0, 32);
    s1 += __shfl_xor(s1, 16); s1 += __shfl_xor(s1, 32);
    fsq0 = s0; fsq1 = s1;
    b00 = pk8(p0[0], p1[0]); b01 = pk8(p0[1], p1[1]);
    b02 = pk8(p0[2], p1[2]); b03 = pk8(p0[3], p1[3]);
    b10 = pk8(q0[0], q1[0]); b11 = pk8(q0[1], q1[1]);
    b12 = pk8(q0[2], q1[2]); b13 = pk8(q0[3], q1[3]);
  }
  asm volatile("s_waitcnt vmcnt(0)" ::: "memory");
  __builtin_amdgcn_s_barrier();

  // A-read addressing: byte = row*128 + ((ks*32+hi*8) ^ ((row&15)<<3))
  const unsigned char* ab = smem + n * 128 + ((hi ^ (n & 3)) << 3);
  const int nh = n >> 2;
  const unsigned char* bk0 = ab + ((0 ^ nh) << 5);
  const unsigned char* bk1 = ab + ((1 ^ nh) << 5);
  const unsigned char* bk2 = ab + ((2 ^ nh) << 5);
  const unsigned char* bk3 = ab + ((3 ^ nh) << 5);

  const float NINF = __builtin_bit_cast(float, 0xFF800000u);
  float top0[8], top1[8];
#pragma unroll
  for (int p = 0; p < 8; ++p) { top0[p] = NINF; top1[p] = NINF; }

  const int stw = wid * 4;   // stagger: wave w starts at group 4w (breaks convoy)
#pragma unroll 4
  for (int pp = 0; pp < 32; ++pp) {
    const int g = (pp + stw) & 31;
    const int off = g * 4096;
    const float* eb = esqmLds + g * 32 + hi * 4;
    f32x4 e0 = *(const f32x4*)(eb);
    f32x4 e1 = *(const f32x4*)(eb + 16);
    long long t0 = *(const long long*)(bk0 + off);
    long long t1 = *(const long long*)(bk1 + off);
    long long t2 = *(const long long*)(bk2 + off);
    long long t3 = *(const long long*)(bk3 + off);
    long long u0 = *(const long long*)(bk0 + off + 2048);
    long long u1 = *(const long long*)(bk1 + off + 2048);
    long long u2 = *(const long long*)(bk2 + off + 2048);
    long long u3 = *(const long long*)(bk3 + off + 2048);
    // 4 independent 4-deep MFMA chains (2 row-sets x 2 code-subgroups)
    f32x4 a0 = e0, a1 = e1, a2 = e0, a3 = e1;
    a0 = mfma8(t0, b00, a0); a1 = mfma8(u0, b00, a1);
    a2 = mfma8(t0, b10, a2); a3 = mfma8(u0, b10, a3);
    a0 = mfma8(t1, b01, a0); a1 = mfma8(u1, b01, a1);
    a2 = mfma8(t1, b11, a2); a3 = mfma8(u1, b11, a3);
    a0 = mfma8(t2, b02, a0); a1 = mfma8(u2, b02, a1);
    a2 = mfma8(t2, b12, a2); a3 = mfma8(u2, b12, a3);
    a0 = mfma8(t3, b03, a0); a1 = mfma8(u3, b03, a1);
    a2 = mfma8(t3, b13, a2); a3 = mfma8(u3, b13, a3);

    const int cb = g * 32 + hi * 4;
    {   // set 0: cell-of-8 max -> one insert
      float k0 = packk(a0[0], cb + 0),  k1 = packk(a0[1], cb + 1);
      float k2 = packk(a0[2], cb + 2),  k3 = packk(a0[3], cb + 3);
      float k4 = packk(a1[0], cb + 16), k5 = packk(a1[1], cb + 17);
      float k6 = packk(a1[2], cb + 18), k7 = packk(a1[3], cb + 19);
      float x = fmaxf(fmaxf(fmaxf(k0, k1), fmaxf(k2, k3)),
                      fmaxf(fmaxf(k4, k5), fmaxf(k6, k7)));
      ins8(top0, x);
    }
    {   // set 1
      float k0 = packk(a2[0], cb + 0),  k1 = packk(a2[1], cb + 1);
      float k2 = packk(a2[2], cb + 2),  k3 = packk(a2[3], cb + 3);
      float k4 = packk(a3[0], cb + 16), k5 = packk(a3[1], cb + 17);
      float k6 = packk(a3[2], cb + 18), k7 = packk(a3[3], cb + 19);
      float x = fmaxf(fmaxf(fmaxf(k0, k1), fmaxf(k2, k3)),
                      fmaxf(fmaxf(k4, k5), fmaxf(k6, k7)));
      ins8(top1, x);
    }
  }

  int kk = ksel[lane & 7];                 // row&7 == n&7 == lane&7 for both sets
  kk = kk < 0 ? 0 : (kk > 7 ? 7 : kk);

  // set 0: combine hi-lanes, pick k-th, write rows
  merge8(top0, 16); merge8(top0, 32);
  float sel0 = top0[0];
#pragma unroll
  for (int p = 1; p < 8; ++p) sel0 = (kk == p) ? top0[p] : sel0;
  unsigned sb0 = __builtin_bit_cast(unsigned, sel0);
  int idx0 = (int)(sb0 & 1023u);
  float rl0 = fsq0 - __builtin_bit_cast(float, sb0 & 0xFFFFFC00u) * (1.0f / 512.0f);
  write_rows(emb, out, gR0 + wid * 32, idx0, lane);

  // set 1
  merge8(top1, 16); merge8(top1, 32);
  float sel1 = top1[0];
#pragma unroll
  for (int p = 1; p < 8; ++p) sel1 = (kk == p) ? top1[p] : sel1;
  unsigned sb1 = __builtin_bit_cast(unsigned, sel1);
  int idx1 = (int)(sb1 & 1023u);
  float rl1 = fsq1 - __builtin_bit_cast(float, sb1 & 0xFFFFFC00u) * (1.0f / 512.0f);
  write_rows(emb, out, gR0 + wid * 32 + 16, idx1, lane);

  // deterministic loss: per-block double sum -> fixed-point int64 atomic;
  // last block converts (integer adds associative -> replay-stable)
  float c = (lane < 16) ? (rl0 + rl1) : 0.f;
#pragma unroll
  for (int m = 1; m <= 32; m <<= 1) c += __shfl_xor(c, m);
  if (lane == 0) wLds[wid] = c;
  __syncthreads();
  if (tid == 0) {
    double bs = 0.0;
#pragma unroll
    for (int w = 0; w < 8; ++w) bs += (double)wLds[w];
    long long iv = (long long)(bs * 1048576.0 + 0.5);
    atomicAdd(lossAcc, (unsigned long long)iv);
    __threadfence();
    unsigned done = atomicAdd(cnt, 1u);
    if (done == 255u) {
      unsigned long long tot = atomicAdd(lossAcc, 0ULL);
      loss[0] = (float)((double)(long long)tot * (1.25 / (1048576.0 * 8388608.0)));
    }
  }
}

extern "C" void kernel_launch(void* const* d_in, const int* in_sizes, int n_in,
                              void* d_out, int out_size, void* d_ws, size_t ws_size,
                              hipStream_t stream) {
  const float* lat = (const float*)d_in[0];   // [8192,1024] fp32
  const float* emb = (const float*)d_in[1];   // [1024,128]  fp32
  const int* ksel = (const int*)d_in[2];      // [8] int32
  float* out = (float*)d_out;                 // quantized[8388608] + loss[1]

  unsigned char* ebf8 = (unsigned char*)d_ws;                 // 131072 B swizzled fp8 codes
  float* esqm = (float*)((char*)d_ws + 131072);               // 4096 B (-512*||e||^2)
  unsigned long long* lossAcc =
      (unsigned long long*)((char*)d_ws + 135168);            // 8 B fixed-point loss
  unsigned* cnt = (unsigned*)((char*)d_ws + 135176);          // 4 B block counter

  vq_prep<<<1024, 128, 0, stream>>>(emb, ebf8, esqm, lossAcc, cnt);
  vq_main<<<256, 512, 0, stream>>>(lat, emb, ksel, ebf8, esqm, out, lossAcc, cnt,
                                   out + NELEM);
}